// Round 11
// baseline (748.040 us; speedup 1.0000x reference)
//
#include <hip/hip_runtime.h>
#include <math.h>

#define BQ    8192
#define DIMD  256
#define NSUB  16
#define KC    1024
#define ED    16
#define SCW   32                            // scans per wave (2 C-tiles)

#define OFF_ZQ   1
#define OFF_OH   (1 + BQ * DIMD)            // 2097153
#define OH_ELEMS (BQ * NSUB * KC)           // 134217728
#define OFF_IDX  (OFF_OH + OH_ELEMS)        // 136314881
#define F4N      ((OH_ELEMS - 4) / 4)       // 33554431 aligned float4 slots
#define FTHR     (1024 * 256)               // fill threads (odd blocks)

typedef __attribute__((ext_vector_type(2))) float v2f;
typedef __attribute__((ext_vector_type(4))) float f32x4;
typedef __attribute__((ext_vector_type(8))) short bshort8;
typedef __attribute__((ext_vector_type(4))) unsigned int u32x4;

struct Zr  { v2f p0, p1, p2, p3, p4, p5, p6, p7; };   // one residual (16 f)
struct Row { float4 c0, c1, c2, c3; };                 // one codebook row
struct V2x2 { v2f lo, hi; };

// numpy pairwise sum-of-squares (verified R3).
__device__ __forceinline__ float np_sumsq(Zr z) {
  float q0 = __fmul_rn(z.p0.x, z.p0.x), q1 = __fmul_rn(z.p0.y, z.p0.y);
  float q2 = __fmul_rn(z.p1.x, z.p1.x), q3 = __fmul_rn(z.p1.y, z.p1.y);
  float q4 = __fmul_rn(z.p2.x, z.p2.x), q5 = __fmul_rn(z.p2.y, z.p2.y);
  float q6 = __fmul_rn(z.p3.x, z.p3.x), q7 = __fmul_rn(z.p3.y, z.p3.y);
  float q8 = __fmul_rn(z.p4.x, z.p4.x), q9 = __fmul_rn(z.p4.y, z.p4.y);
  float qa = __fmul_rn(z.p5.x, z.p5.x), qb = __fmul_rn(z.p5.y, z.p5.y);
  float qc = __fmul_rn(z.p6.x, z.p6.x), qd = __fmul_rn(z.p6.y, z.p6.y);
  float qe = __fmul_rn(z.p7.x, z.p7.x), qf = __fmul_rn(z.p7.y, z.p7.y);
  float r0 = __fadd_rn(q0, q8), r1 = __fadd_rn(q1, q9);
  float r2 = __fadd_rn(q2, qa), r3 = __fadd_rn(q3, qb);
  float r4 = __fadd_rn(q4, qc), r5 = __fadd_rn(q5, qd);
  float r6 = __fadd_rn(q6, qe), r7 = __fadd_rn(q7, qf);
  return __fadd_rn(__fadd_rn(__fadd_rn(r0, r1), __fadd_rn(r2, r3)),
                   __fadd_rn(__fadd_rn(r4, r5), __fadd_rn(r6, r7)));
}

// Reference-rounded distance (verified R3): SSE-lane einsum SOP + hadd,
// step-rounded d^2 assembly, fp64 sqrt (correctly rounded, CPU-bit-exact).
__device__ __forceinline__ float ref_d(Zr z, Row rw, float zsq, float esq) {
  float p0  = __fmul_rn(z.p0.x, rw.c0.x), p1  = __fmul_rn(z.p0.y, rw.c0.y);
  float p2  = __fmul_rn(z.p1.x, rw.c0.z), p3  = __fmul_rn(z.p1.y, rw.c0.w);
  float p4  = __fmul_rn(z.p2.x, rw.c1.x), p5  = __fmul_rn(z.p2.y, rw.c1.y);
  float p6  = __fmul_rn(z.p3.x, rw.c1.z), p7  = __fmul_rn(z.p3.y, rw.c1.w);
  float p8  = __fmul_rn(z.p4.x, rw.c2.x), p9  = __fmul_rn(z.p4.y, rw.c2.y);
  float p10 = __fmul_rn(z.p5.x, rw.c2.z), p11 = __fmul_rn(z.p5.y, rw.c2.w);
  float p12 = __fmul_rn(z.p6.x, rw.c3.x), p13 = __fmul_rn(z.p6.y, rw.c3.y);
  float p14 = __fmul_rn(z.p7.x, rw.c3.z), p15 = __fmul_rn(z.p7.y, rw.c3.w);
  float L0 = __fadd_rn(__fadd_rn(__fadd_rn(p0, p4), p8),  p12);
  float L1 = __fadd_rn(__fadd_rn(__fadd_rn(p1, p5), p9),  p13);
  float L2 = __fadd_rn(__fadd_rn(__fadd_rn(p2, p6), p10), p14);
  float L3 = __fadd_rn(__fadd_rn(__fadd_rn(p3, p7), p11), p15);
  float cross = __fadd_rn(__fadd_rn(L0, L1), __fadd_rn(L2, L3));
  float t = __fsub_rn(zsq, __fmul_rn(2.0f, cross));
  t = __fadd_rn(t, esq);
  t = fmaxf(t, 0.0f);
  return (float)sqrt((double)t);
}

// scalar fast value (packed fp32 FMA) — fallback gate only (~3e-7 err)
__device__ __forceinline__ float fastv_s(Zr z, Row rw, float eh) {
  V2x2 a0 = __builtin_bit_cast(V2x2, rw.c0);
  V2x2 a1 = __builtin_bit_cast(V2x2, rw.c1);
  V2x2 a2 = __builtin_bit_cast(V2x2, rw.c2);
  V2x2 a3 = __builtin_bit_cast(V2x2, rw.c3);
  v2f accA = {eh, 0.f}, accB = {0.f, 0.f};
  accA = __builtin_elementwise_fma(-z.p0, a0.lo, accA);
  accB = __builtin_elementwise_fma(-z.p1, a0.hi, accB);
  accA = __builtin_elementwise_fma(-z.p2, a1.lo, accA);
  accB = __builtin_elementwise_fma(-z.p3, a1.hi, accB);
  accA = __builtin_elementwise_fma(-z.p4, a2.lo, accA);
  accB = __builtin_elementwise_fma(-z.p5, a2.hi, accB);
  accA = __builtin_elementwise_fma(-z.p6, a3.lo, accA);
  accB = __builtin_elementwise_fma(-z.p7, a3.hi, accB);
  v2f acc = accA + accB;
  return acc.x + acc.y;
}

__device__ __forceinline__ Zr sub_row(Zr z, Row rw) {   // elementwise __fsub_rn
  Zr o;
  o.p0 = (v2f){__fsub_rn(z.p0.x, rw.c0.x), __fsub_rn(z.p0.y, rw.c0.y)};
  o.p1 = (v2f){__fsub_rn(z.p1.x, rw.c0.z), __fsub_rn(z.p1.y, rw.c0.w)};
  o.p2 = (v2f){__fsub_rn(z.p2.x, rw.c1.x), __fsub_rn(z.p2.y, rw.c1.y)};
  o.p3 = (v2f){__fsub_rn(z.p3.x, rw.c1.z), __fsub_rn(z.p3.y, rw.c1.w)};
  o.p4 = (v2f){__fsub_rn(z.p4.x, rw.c2.x), __fsub_rn(z.p4.y, rw.c2.y)};
  o.p5 = (v2f){__fsub_rn(z.p5.x, rw.c2.z), __fsub_rn(z.p5.y, rw.c2.w)};
  o.p6 = (v2f){__fsub_rn(z.p6.x, rw.c3.x), __fsub_rn(z.p6.y, rw.c3.y)};
  o.p7 = (v2f){__fsub_rn(z.p7.x, rw.c3.z), __fsub_rn(z.p7.y, rw.c3.w)};
  return o;
}

__device__ __forceinline__ Zr load_zr(const float* p) {
  const float4* zp = (const float4*)p;
  float4 a0 = zp[0], a1 = zp[1], a2 = zp[2], a3 = zp[3];
  V2x2 v0 = __builtin_bit_cast(V2x2, a0), v1 = __builtin_bit_cast(V2x2, a1);
  V2x2 v2 = __builtin_bit_cast(V2x2, a2), v3 = __builtin_bit_cast(V2x2, a3);
  Zr z;
  z.p0 = v0.lo; z.p1 = v0.hi; z.p2 = v1.lo; z.p3 = v1.hi;
  z.p4 = v2.lo; z.p5 = v2.hi; z.p6 = v3.lo; z.p7 = v3.hi;
  return z;
}

__device__ __forceinline__ Row load_row(const float* p) {
  const float4* cp = (const float4*)p;
  Row rw; rw.c0 = cp[0]; rw.c1 = cp[1]; rw.c2 = cp[2]; rw.c3 = cp[3];
  return rw;
}

__device__ __forceinline__ float l1norm(Zr z) {
  float t0 = fabsf(z.p0.x) + fabsf(z.p0.y), t1 = fabsf(z.p1.x) + fabsf(z.p1.y);
  float t2 = fabsf(z.p2.x) + fabsf(z.p2.y), t3 = fabsf(z.p3.x) + fabsf(z.p3.y);
  float t4 = fabsf(z.p4.x) + fabsf(z.p4.y), t5 = fabsf(z.p5.x) + fabsf(z.p5.y);
  float t6 = fabsf(z.p6.x) + fabsf(z.p6.y), t7 = fabsf(z.p7.x) + fabsf(z.p7.y);
  return ((t0 + t1) + (t2 + t3)) + ((t4 + t5) + (t6 + t7));
}

// fp32 -> bf16 (RNE) and back; fast-path only (window absorbs any mode diff).
__device__ __forceinline__ unsigned int f2bf(float x) {
  unsigned int u = __float_as_uint(x);
  return (u + 0x7FFFu + ((u >> 16) & 1u)) >> 16;
}
__device__ __forceinline__ float bf2f(unsigned int b) {
  return __uint_as_float(b << 16);
}

// stage one residual: fp32 copy + bf16 hi/lo split (identical math to R7)
__device__ __forceinline__ void stage_zr(Zr zr, unsigned int* zqp, float* zbp) {
  v2f* zb2 = (v2f*)zbp;
  zb2[0]=zr.p0; zb2[1]=zr.p1; zb2[2]=zr.p2; zb2[3]=zr.p3;
  zb2[4]=zr.p4; zb2[5]=zr.p5; zb2[6]=zr.p6; zb2[7]=zr.p7;
  v2f P; unsigned h0, h1, l0, l1;
#define PK(I, PP)                                                             \
  P = PP; h0 = f2bf(P.x); h1 = f2bf(P.y); zqp[I] = h0 | (h1 << 16);           \
  l0 = f2bf(__fsub_rn(P.x, bf2f(h0))); l1 = f2bf(__fsub_rn(P.y, bf2f(h1)));   \
  zqp[8 + I] = l0 | (l1 << 16);
  PK(0, zr.p0) PK(1, zr.p1) PK(2, zr.p2) PK(3, zr.p3)
  PK(4, zr.p4) PK(5, zr.p5) PK(6, zr.p6) PK(7, zr.p7)
#undef PK
}

// ---------------------------------------------------------------------------
// Prep: split-negate codebook into ws A-frag region + esq table.
// ---------------------------------------------------------------------------
__global__ void vq_prep(const float* __restrict__ emb,
                        unsigned int* __restrict__ ws) {
  const int row = blockIdx.x * 256 + threadIdx.x;   // 16384 rows (n*1024+k)
  const float* c = emb + row * 16;
  unsigned int o[16];
#pragma unroll
  for (int u = 0; u < 8; ++u) {
    float a = -c[2 * u], b = -c[2 * u + 1];
    unsigned int h0 = f2bf(a), h1 = f2bf(b);
    o[u] = h0 | (h1 << 16);
    unsigned int l0 = f2bf(__fsub_rn(a, bf2f(h0)));
    unsigned int l1 = f2bf(__fsub_rn(b, bf2f(h1)));
    o[8 + u] = l0 | (l1 << 16);
  }
  u32x4* dst = (u32x4*)ws + row * 4;
#pragma unroll
  for (int j = 0; j < 4; ++j)
    dst[j] = (u32x4){o[4 * j], o[4 * j + 1], o[4 * j + 2], o[4 * j + 3]};
  float* esqg = (float*)(ws + 16384 * 16);
  esqg[row] = np_sumsq(load_zr(c));
}

// ---------------------------------------------------------------------------
// Kernel 1: 2048 blocks, parity-split roles.
//  odd  blocks: pure onehot zero-fill (nt-store burst; no loads => no vmcnt
//               waits; stores drain asynchronously under the compute blocks;
//               the dispatch-end fence orders them before vq_ones).
//  even blocks: R10-verified MFMA scan, fill machinery removed, depth-2
//               A-frag prefetch (loop body ~80cyc < L2 ~200cyc).
// ---------------------------------------------------------------------------
__global__ __launch_bounds__(256, 4) void vq_main(
    const float* __restrict__ z, const float* __restrict__ emb,
    const unsigned int* __restrict__ ws, float* __restrict__ out) {
  __shared__ float esq[KC];                    // 4 KB
  __shared__ float ehs[KC];                    // 4 KB
  __shared__ unsigned int zq[4 * SCW * 16];    // 8 KB bf16-split residuals
  __shared__ float zb[4 * SCW * 16];           // 8 KB fp32 residuals (24 KB)
  const int tid = threadIdx.x;
  const int bx  = blockIdx.x;

  if (bx & 1) {                                // ---- fill role ----
    const int fgtid = (bx >> 1) * 256 + tid;   // 0 .. FTHR-1
    f32x4* f4 = (f32x4*)(out + OFF_OH + 3);    // 16B-aligned
    const f32x4 zf4 = {0.f, 0.f, 0.f, 0.f};
#pragma unroll 8
    for (int s = 0; s < 128; ++s) {
      int sl = s * FTHR + fgtid;               // slot-major: 1KB/wave coalesced
      if (sl < F4N) __builtin_nontemporal_store(zf4, f4 + sl);
    }
    return;
  }

  // ---- compute role ----
  const int cbx   = bx >> 1;                   // 0 .. 1023
  const int n     = cbx & 15;
  const int bbase = (cbx >> 4) * 128;
  const int w     = tid >> 6;
  const int lane  = tid & 63;
  const int q     = lane >> 4;
  const int c16   = lane & 15;
  const int sc    = lane & 31;                 // scan within wave (twin lanes)
  const float* embn = emb + n * (KC * ED);
  const u32x4* wsn  = (const u32x4*)ws + n * (KC * 4);
  const float* esqg = (const float*)(ws + 16384 * 16) + n * KC;

  for (int k = tid; k < KC; k += 256) {
    float s = esqg[k];
    esq[k] = s; ehs[k] = 0.5f * s;
  }
  if (cbx == 0 && tid == 0) {
    out[0] = 0.f;
    out[OFF_OH + 0] = 0.f; out[OFF_OH + 1] = 0.f; out[OFF_OH + 2] = 0.f;
    out[OFF_OH + OH_ELEMS - 1] = 0.f;
  }
  __syncthreads();

  const int scanB = bbase + w * SCW + sc;
  Zr zr = load_zr(z + scanB * DIMD + n * ED);
  unsigned int* zqw = zq + w * (SCW * 16);
  float*        zbw = zb + w * (SCW * 16);
  if (lane < SCW) stage_zr(zr, zqw + sc * 16, zbw + sc * 16);

  int bi = 0;

  for (int dep = 0; dep < 3; ++dep) {
    asm volatile("s_waitcnt lgkmcnt(0)" ::: "memory");
    u32x4 B0u = *(const u32x4*)(zqw + ((0 * 16 + c16) * 16 + q * 4));
    u32x4 B1u = *(const u32x4*)(zqw + ((1 * 16 + c16) * 16 + q * 4));
    bshort8 b0 = __builtin_bit_cast(bshort8, B0u);
    bshort8 b1 = __builtin_bit_cast(bshort8, B1u);

    float m1_0 = 3.0e38f, m1_1 = 3.0e38f;
    float m2_0 = 3.0e38f, m2_1 = 3.0e38f;
    int   k1_0 = 0, k1_1 = 0;
    const int qc4 = q * 4;
    const int aoff = c16 * 4 + q, boff = c16 * 4 + ((q + 2) & 3);

    // depth-2 prefetch: ct=0 and ct=1 in flight
    u32x4 A1p0 = wsn[aoff],      A2p0 = wsn[boff];
    u32x4 A1p1 = wsn[64 + aoff], A2p1 = wsn[64 + boff];
    float4 ehp0 = ((const float4*)ehs)[q];
    float4 ehp1 = ((const float4*)ehs)[4 + q];

    for (int ct = 0; ct < 64; ++ct) {
      u32x4 A1c = A1p0, A2c = A2p0;
      f32x4 ehv = __builtin_bit_cast(f32x4, ehp0);
      A1p0 = A1p1; A2p0 = A2p1; ehp0 = ehp1;
      if (ct < 62) {
        const int nb = (ct + 2) * 64;
        A1p1 = wsn[nb + aoff];
        A2p1 = wsn[nb + boff];
        ehp1 = ((const float4*)ehs)[(ct + 2) * 4 + q];
      }
      bshort8 a1 = __builtin_bit_cast(bshort8, A1c);
      bshort8 a2 = __builtin_bit_cast(bshort8, A2c);
      const int cbase = ct * 16 + qc4;
#define UPD(V, CODE, M1, K1, M2)                                              \
      { float v_ = (V);                                                       \
        M2 = __builtin_amdgcn_fmed3f(v_, M1, M2);                             \
        bool lt_ = v_ < M1; M1 = lt_ ? v_ : M1; K1 = lt_ ? (CODE) : K1; }
#define DOST(BV, M1, K1, M2)                                                  \
      { f32x4 d1 = __builtin_amdgcn_mfma_f32_16x16x32_bf16(a1, BV, ehv, 0,0,0);\
        f32x4 dd = __builtin_amdgcn_mfma_f32_16x16x32_bf16(a2, BV, d1, 0,0,0);\
        UPD(dd.x, cbase + 0, M1, K1, M2)                                      \
        UPD(dd.y, cbase + 1, M1, K1, M2)                                      \
        UPD(dd.z, cbase + 2, M1, K1, M2)                                      \
        UPD(dd.w, cbase + 3, M1, K1, M2) }
      DOST(b0, m1_0, k1_0, m2_0)
      DOST(b1, m1_1, k1_1, m2_1)
#undef DOST
#undef UPD
    }
    // cross-quad reduce: lanes {s, s^16, s^32, s^48} share a scan per tile
#define MERGE3(M1, K1, M2, OFF)                                               \
    { float om = __shfl_xor(M1, OFF); int ok = __shfl_xor(K1, OFF);           \
      float os = __shfl_xor(M2, OFF);                                         \
      float hi = fmaxf(M1, om);                                               \
      M2 = fminf(fminf(M2, os), hi);                                          \
      bool bw = (om < M1) || (om == M1 && ok < K1);                           \
      M1 = bw ? om : M1; K1 = bw ? ok : K1; }
    MERGE3(m1_0, k1_0, m2_0, 16) MERGE3(m1_0, k1_0, m2_0, 32)
    MERGE3(m1_1, k1_1, m2_1, 16) MERGE3(m1_1, k1_1, m2_1, 32)
#undef MERGE3
    // lane (l&31) owns scan l&31; tile = (l&31)>=16
    const bool t1 = (sc >= 16);
    float m1F = t1 ? m1_1 : m1_0;
    float m2F = t1 ? m2_1 : m2_0;
    int   k1F = t1 ? k1_1 : k1_0;

    // per-scan sound ambiguity window (R10-verified)
    const float wepsb = fmaf(l1norm(zr), 1.0e-6f, 1.5e-5f);
    bool fb = (lane < SCW) && (__fsub_rn(m2F, m1F) < wepsb);
    unsigned long long mask = __ballot(fb);
    while (mask) {
      int ss = __ffsll((unsigned long long)mask) - 1;
      mask &= (mask - 1);
      Zr zs = load_zr(zbw + ss * 16);          // broadcast read
      float zsq = np_sumsq(zs);
      float gme = __shfl(m1F, ss) + __shfl(wepsb, ss);   // gate threshold
      float db = 3.0e38f; int kb = 0;
      for (int i = 0; i < 16; ++i) {
        int kk = i * 64 + lane;
        Row rw = load_row(embn + kk * 16);
        if (fastv_s(zs, rw, ehs[kk]) < gme) {  // gate: skip fp64 sqrt
          float d = ref_d(zs, rw, zsq, esq[kk]);
          if (d < db) { db = d; kb = kk; }     // strict < => first within lane
        }
      }
#pragma unroll
      for (int off = 1; off < 64; off <<= 1) { // lexicographic (d,k) min
        float od = __shfl_xor(db, off); int ok = __shfl_xor(kb, off);
        if (od < db || (od == db && ok < kb)) { db = od; kb = ok; }
      }
      if (lane == ss) k1F = kb;
    }
    k1F = __shfl(k1F, sc);                     // twin-broadcast (lanes >= 32)
    bi = k1F;
    // residual update (fp32, ref-exact elementwise chain)
    zr = sub_row(zr, load_row(embn + k1F * 16));
    if (dep < 2 && lane < SCW) stage_zr(zr, zqw + sc * 16, zbw + sc * 16);
  }
  // lanes < 32 write idx + mean(q) = (z_orig - zr_final)/3 (verified path)
  if (lane < SCW) {
    out[OFF_IDX + scanB * NSUB + n] = (float)bi;
    Zr zo = load_zr(z + scanB * DIMD + n * ED);
    float* mp2 = out + OFF_ZQ + scanB * DIMD + n * ED;
    mp2[0]  = __fdiv_rn(__fsub_rn(zo.p0.x, zr.p0.x), 3.0f);
    mp2[1]  = __fdiv_rn(__fsub_rn(zo.p0.y, zr.p0.y), 3.0f);
    mp2[2]  = __fdiv_rn(__fsub_rn(zo.p1.x, zr.p1.x), 3.0f);
    mp2[3]  = __fdiv_rn(__fsub_rn(zo.p1.y, zr.p1.y), 3.0f);
    mp2[4]  = __fdiv_rn(__fsub_rn(zo.p2.x, zr.p2.x), 3.0f);
    mp2[5]  = __fdiv_rn(__fsub_rn(zo.p2.y, zr.p2.y), 3.0f);
    mp2[6]  = __fdiv_rn(__fsub_rn(zo.p3.x, zr.p3.x), 3.0f);
    mp2[7]  = __fdiv_rn(__fsub_rn(zo.p3.y, zr.p3.y), 3.0f);
    mp2[8]  = __fdiv_rn(__fsub_rn(zo.p4.x, zr.p4.x), 3.0f);
    mp2[9]  = __fdiv_rn(__fsub_rn(zo.p4.y, zr.p4.y), 3.0f);
    mp2[10] = __fdiv_rn(__fsub_rn(zo.p5.x, zr.p5.x), 3.0f);
    mp2[11] = __fdiv_rn(__fsub_rn(zo.p5.y, zr.p5.y), 3.0f);
    mp2[12] = __fdiv_rn(__fsub_rn(zo.p6.x, zr.p6.x), 3.0f);
    mp2[13] = __fdiv_rn(__fsub_rn(zo.p6.y, zr.p6.y), 3.0f);
    mp2[14] = __fdiv_rn(__fsub_rn(zo.p7.x, zr.p7.x), 3.0f);
    mp2[15] = __fdiv_rn(__fsub_rn(zo.p7.y, zr.p7.y), 3.0f);
  }
}

// ---------------------------------------------------------------------------
// Kernel 2: scatter the ones into the (already zeroed) onehot region.
// ---------------------------------------------------------------------------
__global__ void vq_ones(float* __restrict__ out) {
  int g = blockIdx.x * 256 + threadIdx.x;          // 0 .. 131071 == b*16+n
  int k = (int)out[OFF_IDX + g];
  out[OFF_OH + g * KC + k] = 1.0f;
}

// ---------------------------------------------------------------------------
// Kernel 3: z_q = mean @ W + b, straight-through output, loss.
// ---------------------------------------------------------------------------
#define TB 16
__global__ __launch_bounds__(256, 2) void vq_head(
    const float* __restrict__ z, const float* __restrict__ W,
    const float* __restrict__ bias, float* __restrict__ out) {
  __shared__ float ml[TB][DIMD];   // 16KB
  __shared__ double reds[4];
  const int t  = threadIdx.x;
  const int r0 = blockIdx.x * TB;
  for (int j = t; j < TB * DIMD; j += 256) {
    int r = j >> 8, d = j & 255;
    ml[r][d] = out[OFF_ZQ + (r0 + r) * DIMD + d];
  }
  __syncthreads();
  float acc[TB];
#pragma unroll
  for (int r = 0; r < TB; ++r) acc[r] = 0.f;
  for (int d = 0; d < DIMD; ++d) {
    float w = W[d * DIMD + t];
#pragma unroll
    for (int r = 0; r < TB; ++r) acc[r] = fmaf(ml[r][d], w, acc[r]);
  }
  const float bv = bias[t];
  double lp = 0.0;
#pragma unroll
  for (int r = 0; r < TB; ++r) {
    float zq   = acc[r] + bv;
    float zv   = z[(r0 + r) * DIMD + t];
    float diff = zq - zv;
    out[OFF_ZQ + (r0 + r) * DIMD + t] = zv + diff;
    lp += (double)diff * (double)diff;
  }
#pragma unroll
  for (int o = 32; o > 0; o >>= 1) lp += __shfl_down(lp, o);
  if ((t & 63) == 0) reds[t >> 6] = lp;
  __syncthreads();
  if (t == 0) {
    double tot = reds[0] + reds[1] + reds[2] + reds[3];
    atomicAdd(out, (float)(tot * (1.25 / (double)(BQ * DIMD))));
  }
}

extern "C" void kernel_launch(void* const* d_in, const int* in_sizes, int n_in,
                              void* d_out, int out_size, void* d_ws, size_t ws_size,
                              hipStream_t stream) {
  const float* z    = (const float*)d_in[0];
  const float* emb  = (const float*)d_in[1];
  const float* W    = (const float*)d_in[2];
  const float* bias = (const float*)d_in[3];
  float* out = (float*)d_out;
  unsigned int* wsp = (unsigned int*)d_ws;       // 1 MB A-frags + 64 KB esq
  vq_prep<<<dim3(64), dim3(256), 0, stream>>>(emb, wsp);
  vq_main<<<dim3(2048), dim3(256), 0, stream>>>(z, emb, wsp, out);
  vq_ones<<<dim3((BQ * NSUB) / 256), dim3(256), 0, stream>>>(out);
  vq_head<<<dim3(BQ / TB), dim3(256), 0, stream>>>(z, W, bias, out);
}